// Round 20
// baseline (1274.877 us; speedup 1.0000x reference)
//
#include <hip/hip_runtime.h>
#include <stdint.h>

// B=4,H=16,S=2048,D=64 fp32 SDPA with materialized attn_prob.
// r20 = r19 (cooperative mask->bits prelude, 943us) +
//  (1) 3-deep K prefetch (krA/B/C, preloaded at VMEM queue head)
//  (2) bitwise mask-apply on packed bf16 (no unpack/cvt round-trip)
//  (3) setprio around QK^T MFMAs as well as PV.
#define SEQ 2048
#define DIM 64
#define QBLK 16
#define NWAVE 8
#define KPW 256
#define NCT 16
#define NCHUNK 8
#define THREADS 512
#define SCALE 0.125f
#define LOG2E 1.4426950408889634f
#define VPAD 18                 // vbuf row stride in bf16 (36 B)
#define NTSTR (32*VPAD + 8)     // nt-subtile stride: 1168 B

typedef __attribute__((ext_vector_type(4))) float f32x4;
typedef __attribute__((ext_vector_type(4))) int   i32x4;
typedef __attribute__((ext_vector_type(8))) __bf16 bf16x8;

union PFrag { unsigned w[4]; bf16x8 f; };

static __device__ __forceinline__ unsigned bfbits(float x) {
    union { __bf16 b; unsigned short u; } cv; cv.b = (__bf16)x; return (unsigned)cv.u;
}
static __device__ __forceinline__ float lo16(unsigned u) { return __uint_as_float(u << 16); }
static __device__ __forceinline__ float hi16(unsigned u) { return __uint_as_float(u & 0xffff0000u); }
static __device__ __forceinline__ bf16x8 cvt8(f32x4 a, f32x4 b) {
    bf16x8 f;
    f[0]=(__bf16)a[0]; f[1]=(__bf16)a[1]; f[2]=(__bf16)a[2]; f[3]=(__bf16)a[3];
    f[4]=(__bf16)b[0]; f[5]=(__bf16)b[1]; f[6]=(__bf16)b[2]; f[7]=(__bf16)b[3];
    return f;
}
static __device__ __forceinline__ unsigned nib4(i32x4 mm) {
    return (mm[0]?1u:0u) | (mm[1]?2u:0u) | (mm[2]?4u:0u) | (mm[3]?8u:0u);
}
// bitwise mask-apply on a packed bf16 pair: halves with mask bit -> bf16(-1e9)
static __device__ __forceinline__ unsigned mapply(unsigned pk, unsigned b_lo,
                                                  unsigned b_hi, unsigned NEG2) {
    unsigned m = (b_lo ? 0xFFFFu : 0u) | (b_hi ? 0xFFFF0000u : 0u);
    return pk ^ ((pk ^ NEG2) & m);
}

struct WaveBuf {
    union {
        __bf16 vbuf[4 * NTSTR];      // V chunk, [nt][k][c] padded
        float  ctx[QBLK * DIM];      // ctx partial (used after PV)
    };
};
struct SharedT {
    WaveBuf sw[NWAVE];               // 37376 B
    unsigned mb[QBLK][65];           // 4160 B: mask bits, padded stride
    float red_m[QBLK][NWAVE];        // 512 B
    float red_s[QBLK][NWAVE];        // 512 B
};

__global__ __launch_bounds__(THREADS, 4)
void sdpa_mfma18(const float* __restrict__ Q, const float* __restrict__ K,
                 const float* __restrict__ V, const int* __restrict__ mask,
                 float* __restrict__ ctx_out, float* __restrict__ prob_out) {
    __shared__ SharedT su;

    // XCD-aware swizzle: 8192 = 8 XCDs x 1024 contiguous q-blocks (8 bh per XCD).
    const int rb   = ((blockIdx.x & 7) << 10) + (blockIdx.x >> 3);
    const int bh   = rb >> 7;
    const int q0   = (rb & 127) * QBLK;
    const int t    = threadIdx.x;
    const int lane = t & 63;
    const int w    = t >> 6;
    const int g    = lane >> 4;          // 0..3
    const int c    = lane & 15;          // lane's q-row (and N-col)

    const size_t bh_off = (size_t)bh * SEQ * DIM;
    const float* Qb = Q + bh_off;
    const float* Kb = K + bh_off;
    const float* Vb = V + bh_off;
    const int*   Mb = mask + (size_t)bh * SEQ * SEQ;
    const int wbase = w * KPW;

    // ---- Q^T B-fragments + K tiles 0,1,2 at HEAD of the VMEM queue ----
    bf16x8 qf[2];
    {
        const float* qr = Qb + (size_t)(q0 + c) * DIM + 8 * g;
        qf[0] = cvt8(*(const f32x4*)(qr),      *(const f32x4*)(qr + 4));
        qf[1] = cvt8(*(const f32x4*)(qr + 32), *(const f32x4*)(qr + 36));
    }
    f32x4 krA[4], krB[4], krC[4];
    {
        const float* k0 = Kb + (size_t)(wbase + c) * DIM + 8 * g;
        krA[0] = *(const f32x4*)(k0);      krA[1] = *(const f32x4*)(k0 + 4);
        krA[2] = *(const f32x4*)(k0 + 32); krA[3] = *(const f32x4*)(k0 + 36);
        const float* k1 = Kb + (size_t)(wbase + 16 + c) * DIM + 8 * g;
        krB[0] = *(const f32x4*)(k1);      krB[1] = *(const f32x4*)(k1 + 4);
        krB[2] = *(const f32x4*)(k1 + 32); krB[3] = *(const f32x4*)(k1 + 36);
        const float* k2 = Kb + (size_t)(wbase + 32 + c) * DIM + 8 * g;
        krC[0] = *(const f32x4*)(k2);      krC[1] = *(const f32x4*)(k2 + 4);
        krC[2] = *(const f32x4*)(k2 + 32); krC[3] = *(const f32x4*)(k2 + 36);
    }
    __builtin_amdgcn_sched_barrier(0);

    // =============== cooperative mask->bits prelude ===============
    {
        const int* mstage = Mb + (size_t)q0 * SEQ + 4 * t;
        i32x4 ms[4];
        #pragma unroll
        for (int r = 0; r < 4; ++r)
            ms[r] = *(const i32x4*)(mstage + (size_t)r * SEQ);
        #pragma unroll
        for (int r = 0; r < QBLK; ++r) {
            i32x4 cur = ms[r & 3];
            if (r + 4 < QBLK)
                ms[r & 3] = *(const i32x4*)(mstage + (size_t)(r + 4) * SEQ);
            unsigned v = nib4(cur) << (4 * (lane & 7));
            v |= __shfl_xor(v, 1);
            v |= __shfl_xor(v, 2);
            v |= __shfl_xor(v, 4);
            if ((lane & 7) == 0)
                su.mb[r][w * 8 + (lane >> 3)] = v;
        }
    }

    // =============== QK^T: pure K/L2 queue, 3-tile-ahead prefetch ===============
    unsigned sc_pk[2 * NCT];             // 64 scores, packed bf16, UNMASKED
    #pragma unroll
    for (int ct = 0; ct < NCT; ++ct) {
        const int sel = ct % 3;
        bf16x8 kf0, kf1;
        if (sel == 0)      { kf0 = cvt8(krA[0], krA[1]); kf1 = cvt8(krA[2], krA[3]); }
        else if (sel == 1) { kf0 = cvt8(krB[0], krB[1]); kf1 = cvt8(krB[2], krB[3]); }
        else               { kf0 = cvt8(krC[0], krC[1]); kf1 = cvt8(krC[2], krC[3]); }
        if (ct + 3 < NCT) {  // reload the freed buffer with tile ct+3
            const float* kn = Kb + (size_t)(wbase + (ct + 3) * 16 + c) * DIM + 8 * g;
            if (sel == 0) {
                krA[0] = *(const f32x4*)(kn);      krA[1] = *(const f32x4*)(kn + 4);
                krA[2] = *(const f32x4*)(kn + 32); krA[3] = *(const f32x4*)(kn + 36);
            } else if (sel == 1) {
                krB[0] = *(const f32x4*)(kn);      krB[1] = *(const f32x4*)(kn + 4);
                krB[2] = *(const f32x4*)(kn + 32); krB[3] = *(const f32x4*)(kn + 36);
            } else {
                krC[0] = *(const f32x4*)(kn);      krC[1] = *(const f32x4*)(kn + 4);
                krC[2] = *(const f32x4*)(kn + 32); krC[3] = *(const f32x4*)(kn + 36);
            }
        }
        f32x4 acc = {0.f, 0.f, 0.f, 0.f};
        __builtin_amdgcn_s_setprio(1);
        acc = __builtin_amdgcn_mfma_f32_16x16x32_bf16(kf0, qf[0], acc, 0, 0, 0);
        acc = __builtin_amdgcn_mfma_f32_16x16x32_bf16(kf1, qf[1], acc, 0, 0, 0);
        __builtin_amdgcn_s_setprio(0);
        sc_pk[2 * ct]     = bfbits(acc[0] * SCALE) | (bfbits(acc[1] * SCALE) << 16);
        sc_pk[2 * ct + 1] = bfbits(acc[2] * SCALE) | (bfbits(acc[3] * SCALE) << 16);
    }

    // ---- V chunk-0 prefetch: in flight across both barriers ----
    const int r_st = lane >> 4;
    const int cw   = (4 * c) & 15;
    const int ntw  = c >> 2;
    f32x4 vrawA[4], vrawB[4];
    {
        const float* vsrc = Vb + (size_t)(wbase + r_st) * DIM + 4 * c;
        #pragma unroll
        for (int i = 0; i < 4; ++i) {
            vrawA[i] = *(const f32x4*)(vsrc + (size_t)(4 * i) * DIM);
            vrawB[i] = *(const f32x4*)(vsrc + (size_t)(16 + 4 * i) * DIM);
        }
    }

    __syncthreads();   // barrier #1: mb bits visible

    // apply mask bits from LDS, bitwise on packed bf16 pairs
    const unsigned NEG2 = bfbits(-1e9f) | (bfbits(-1e9f) << 16);
    #pragma unroll
    for (int j = 0; j < 8; ++j) {
        unsigned word = su.mb[c][w * 8 + j];
        unsigned nibE = (word >> (4 * g)) & 0xFu;        // tile ct = 2j
        unsigned nibO = (word >> (16 + 4 * g)) & 0xFu;   // tile ct = 2j+1
        sc_pk[4 * j]     = mapply(sc_pk[4 * j],     nibE & 1u, nibE & 2u, NEG2);
        sc_pk[4 * j + 1] = mapply(sc_pk[4 * j + 1], nibE & 4u, nibE & 8u, NEG2);
        sc_pk[4 * j + 2] = mapply(sc_pk[4 * j + 2], nibO & 1u, nibO & 2u, NEG2);
        sc_pk[4 * j + 3] = mapply(sc_pk[4 * j + 3], nibO & 4u, nibO & 8u, NEG2);
    }

    // =============== single-exchange softmax: wave-local (mx, s_w) ===============
    float mx = -3e38f;
    #pragma unroll
    for (int i = 0; i < 2 * NCT; ++i)
        mx = fmaxf(mx, fmaxf(lo16(sc_pk[i]), hi16(sc_pk[i])));
    mx = fmaxf(mx, __shfl_xor(mx, 16));
    mx = fmaxf(mx, __shfl_xor(mx, 32));

    float sw_ = 0.f;
    #pragma unroll
    for (int i = 0; i < 2 * NCT; ++i) {
        float e0 = exp2f((lo16(sc_pk[i]) - mx) * LOG2E);
        float e1 = exp2f((hi16(sc_pk[i]) - mx) * LOG2E);
        sw_ += e0 + e1;
        sc_pk[i] = bfbits(e0) | (bfbits(e1) << 16);   // e' (wave-relative), bf16-packed
    }
    sw_ += __shfl_xor(sw_, 16);
    sw_ += __shfl_xor(sw_, 32);
    if (g == 0) { su.red_m[c][w] = mx; su.red_s[c][w] = sw_; }
    __syncthreads();   // barrier #2: (m,s) exchange

    float fac;
    {
        float M = su.red_m[c][0];
        #pragma unroll
        for (int i = 1; i < NWAVE; ++i) M = fmaxf(M, su.red_m[c][i]);
        float S = 0.f;
        #pragma unroll
        for (int i = 0; i < NWAVE; ++i)
            S += su.red_s[c][i] * exp2f((su.red_m[c][i] - M) * LOG2E);
        fac = exp2f((mx - M) * LOG2E) / S;
    }
    float facr[4];
    #pragma unroll
    for (int jr = 0; jr < 4; ++jr) facr[jr] = __shfl(fac, 4 * g + jr);

    // =============== PV + prob write; P-fragment via shfl ===============
    f32x4 cacc[4];
    #pragma unroll
    for (int nt = 0; nt < 4; ++nt) cacc[nt] = (f32x4){0.f, 0.f, 0.f, 0.f};

    const int  sA  = ((g & 1) << 5) + c;   // pf source lanes
    const int  sB  = sA + 16;
    const bool hiT = (g >> 1) != 0;

    float* prow = prob_out + ((size_t)bh * SEQ + (q0 + c)) * SEQ + wbase;
    __bf16* vbufW = su.sw[w].vbuf;

    #pragma unroll
    for (int cc = 0; cc < NCHUNK; ++cc) {
        // stage chunk loaded last iteration / prologue
        #pragma unroll
        for (int i = 0; i < 4; ++i) {
            ushort2 lo_, hi_;
            lo_.x = (unsigned short)bfbits(vrawA[i][0]);
            lo_.y = (unsigned short)bfbits(vrawA[i][1]);
            hi_.x = (unsigned short)bfbits(vrawA[i][2]);
            hi_.y = (unsigned short)bfbits(vrawA[i][3]);
            __bf16* p = &vbufW[ntw * NTSTR + (4 * i + r_st) * VPAD + cw];
            *(ushort2*)p = lo_;
            *(ushort2*)(p + 2) = hi_;
        }
        #pragma unroll
        for (int i = 0; i < 4; ++i) {
            ushort2 lo_, hi_;
            lo_.x = (unsigned short)bfbits(vrawB[i][0]);
            lo_.y = (unsigned short)bfbits(vrawB[i][1]);
            hi_.x = (unsigned short)bfbits(vrawB[i][2]);
            hi_.y = (unsigned short)bfbits(vrawB[i][3]);
            __bf16* p = &vbufW[ntw * NTSTR + (16 + 4 * i + r_st) * VPAD + cw];
            *(ushort2*)p = lo_;
            *(ushort2*)(p + 2) = hi_;
        }
        // issue NEXT chunk's loads
        if (cc + 1 < NCHUNK) {
            const float* vsrc = Vb + (size_t)(wbase + (cc + 1) * 32 + r_st) * DIM + 4 * c;
            #pragma unroll
            for (int i = 0; i < 4; ++i) {
                vrawA[i] = *(const f32x4*)(vsrc + (size_t)(4 * i) * DIM);
                vrawB[i] = *(const f32x4*)(vsrc + (size_t)(16 + 4 * i) * DIM);
            }
        }

        // prob writes: pn = e' * fac (normalized)
        unsigned w0 = sc_pk[4 * cc],     w1 = sc_pk[4 * cc + 1];
        unsigned w2 = sc_pk[4 * cc + 2], w3 = sc_pk[4 * cc + 3];
        {
            f32x4 pnA = { lo16(w0) * fac, hi16(w0) * fac, lo16(w1) * fac, hi16(w1) * fac };
            f32x4 pnB = { lo16(w2) * fac, hi16(w2) * fac, lo16(w3) * fac, hi16(w3) * fac };
            *(f32x4*)(prow + 32 * cc + 4 * g)      = pnA;
            *(f32x4*)(prow + 32 * cc + 16 + 4 * g) = pnB;
        }

        // P A-fragment via cross-lane shfl
        PFrag pf;
        {
            unsigned a0 = __shfl(w0, sA), b0 = __shfl(w2, sA);
            pf.w[0] = hiT ? b0 : a0;
            unsigned a1 = __shfl(w1, sA), b1 = __shfl(w3, sA);
            pf.w[1] = hiT ? b1 : a1;
            unsigned a2 = __shfl(w0, sB), b2 = __shfl(w2, sB);
            pf.w[2] = hiT ? b2 : a2;
            unsigned a3 = __shfl(w1, sB), b3 = __shfl(w3, sB);
            pf.w[3] = hiT ? b3 : a3;
        }

        // V B-frags: conflict-free scalar column reads
        bf16x8 vfr[4];
        #pragma unroll
        for (int nt = 0; nt < 4; ++nt) {
            bf16x8 f;
            #pragma unroll
            for (int j = 0; j < 8; ++j)
                f[j] = vbufW[nt * NTSTR + (8 * g + j) * VPAD + c];
            vfr[nt] = f;
        }

        __builtin_amdgcn_s_setprio(1);
        #pragma unroll
        for (int nt = 0; nt < 4; ++nt)
            cacc[nt] = __builtin_amdgcn_mfma_f32_16x16x32_bf16(pf.f, vfr[nt], cacc[nt], 0, 0, 0);
        __builtin_amdgcn_s_setprio(0);
    }

    // =============== ctx partials (scaled by per-row fac) + cross-wave reduce ===============
    #pragma unroll
    for (int nt = 0; nt < 4; ++nt)
        #pragma unroll
        for (int jr = 0; jr < 4; ++jr)
            su.sw[w].ctx[(4 * g + jr) * DIM + nt * 16 + c] = cacc[nt][jr] * facr[jr];
    __syncthreads();
    {
        int e = t * 2;
        float2 a = make_float2(0.f, 0.f);
        #pragma unroll
        for (int i = 0; i < NWAVE; ++i) {
            float2 v = *(const float2*)&su.sw[i].ctx[e];
            a.x += v.x; a.y += v.y;
        }
        *(float2*)(ctx_out + ((size_t)bh * SEQ + q0) * DIM + e) = a;
    }
}

extern "C" void kernel_launch(void* const* d_in, const int* in_sizes, int n_in,
                              void* d_out, int out_size, void* d_ws, size_t ws_size,
                              hipStream_t stream) {
    const float* Q = (const float*)d_in[0];
    const float* K = (const float*)d_in[1];
    const float* V = (const float*)d_in[2];
    const int* mask = (const int*)d_in[3];
    float* ctx  = (float*)d_out;
    float* prob = (float*)d_out + (size_t)4 * 16 * SEQ * DIM;

    dim3 grid(64 * (SEQ / QBLK));   // 8192, divisible by 8 XCDs
    dim3 block(THREADS);
    sdpa_mfma18<<<grid, block, 0, stream>>>(Q, K, V, mask, ctx, prob);
}

// Round 21
// 1177.559 us; speedup vs baseline: 1.0826x; 1.0826x over previous
//
#include <hip/hip_runtime.h>
#include <stdint.h>

// B=4,H=16,S=2048,D=64 fp32 SDPA with materialized attn_prob.
// r21 = r19 (cooperative mask->bits prelude, 943us, 2-deep K prefetch) +
// the two REGISTER-NEUTRAL pieces of r20:
//  (a) bitwise mask-apply on packed bf16 (no unpack/cvt round-trip)
//  (b) setprio around QK^T MFMAs.
// r20's 3-deep K prefetch is DROPPED (it spilled: WRITE 1.245->2.114 GB).
#define SEQ 2048
#define DIM 64
#define QBLK 16
#define NWAVE 8
#define KPW 256
#define NCT 16
#define NCHUNK 8
#define THREADS 512
#define SCALE 0.125f
#define LOG2E 1.4426950408889634f
#define VPAD 18                 // vbuf row stride in bf16 (36 B)
#define NTSTR (32*VPAD + 8)     // nt-subtile stride: 1168 B

typedef __attribute__((ext_vector_type(4))) float f32x4;
typedef __attribute__((ext_vector_type(4))) int   i32x4;
typedef __attribute__((ext_vector_type(8))) __bf16 bf16x8;

union PFrag { unsigned w[4]; bf16x8 f; };

static __device__ __forceinline__ unsigned bfbits(float x) {
    union { __bf16 b; unsigned short u; } cv; cv.b = (__bf16)x; return (unsigned)cv.u;
}
static __device__ __forceinline__ float lo16(unsigned u) { return __uint_as_float(u << 16); }
static __device__ __forceinline__ float hi16(unsigned u) { return __uint_as_float(u & 0xffff0000u); }
static __device__ __forceinline__ bf16x8 cvt8(f32x4 a, f32x4 b) {
    bf16x8 f;
    f[0]=(__bf16)a[0]; f[1]=(__bf16)a[1]; f[2]=(__bf16)a[2]; f[3]=(__bf16)a[3];
    f[4]=(__bf16)b[0]; f[5]=(__bf16)b[1]; f[6]=(__bf16)b[2]; f[7]=(__bf16)b[3];
    return f;
}
static __device__ __forceinline__ unsigned nib4(i32x4 mm) {
    return (mm[0]?1u:0u) | (mm[1]?2u:0u) | (mm[2]?4u:0u) | (mm[3]?8u:0u);
}
// bitwise mask-apply on a packed bf16 pair: halves with mask bit -> bf16(-1e9)
static __device__ __forceinline__ unsigned mapply(unsigned pk, unsigned b_lo,
                                                  unsigned b_hi, unsigned NEG2) {
    unsigned m = (b_lo ? 0xFFFFu : 0u) | (b_hi ? 0xFFFF0000u : 0u);
    return pk ^ ((pk ^ NEG2) & m);
}

struct WaveBuf {
    union {
        __bf16 vbuf[4 * NTSTR];      // V chunk, [nt][k][c] padded
        float  ctx[QBLK * DIM];      // ctx partial (used after PV)
    };
};
struct SharedT {
    WaveBuf sw[NWAVE];               // 37376 B
    unsigned mb[QBLK][65];           // 4160 B: mask bits, padded stride
    float red_m[QBLK][NWAVE];        // 512 B
    float red_s[QBLK][NWAVE];        // 512 B
};

__global__ __launch_bounds__(THREADS, 4)
void sdpa_mfma19(const float* __restrict__ Q, const float* __restrict__ K,
                 const float* __restrict__ V, const int* __restrict__ mask,
                 float* __restrict__ ctx_out, float* __restrict__ prob_out) {
    __shared__ SharedT su;

    // XCD-aware swizzle: 8192 = 8 XCDs x 1024 contiguous q-blocks (8 bh per XCD).
    const int rb   = ((blockIdx.x & 7) << 10) + (blockIdx.x >> 3);
    const int bh   = rb >> 7;
    const int q0   = (rb & 127) * QBLK;
    const int t    = threadIdx.x;
    const int lane = t & 63;
    const int w    = t >> 6;
    const int g    = lane >> 4;          // 0..3
    const int c    = lane & 15;          // lane's q-row (and N-col)

    const size_t bh_off = (size_t)bh * SEQ * DIM;
    const float* Qb = Q + bh_off;
    const float* Kb = K + bh_off;
    const float* Vb = V + bh_off;
    const int*   Mb = mask + (size_t)bh * SEQ * SEQ;
    const int wbase = w * KPW;

    // ---- Q^T B-fragments + K tiles 0,1 at HEAD of the VMEM queue ----
    bf16x8 qf[2];
    {
        const float* qr = Qb + (size_t)(q0 + c) * DIM + 8 * g;
        qf[0] = cvt8(*(const f32x4*)(qr),      *(const f32x4*)(qr + 4));
        qf[1] = cvt8(*(const f32x4*)(qr + 32), *(const f32x4*)(qr + 36));
    }
    f32x4 krA[4], krB[4];
    {
        const float* k0 = Kb + (size_t)(wbase + c) * DIM + 8 * g;
        krA[0] = *(const f32x4*)(k0);      krA[1] = *(const f32x4*)(k0 + 4);
        krA[2] = *(const f32x4*)(k0 + 32); krA[3] = *(const f32x4*)(k0 + 36);
        const float* k1 = Kb + (size_t)(wbase + 16 + c) * DIM + 8 * g;
        krB[0] = *(const f32x4*)(k1);      krB[1] = *(const f32x4*)(k1 + 4);
        krB[2] = *(const f32x4*)(k1 + 32); krB[3] = *(const f32x4*)(k1 + 36);
    }
    __builtin_amdgcn_sched_barrier(0);

    // =============== cooperative mask->bits prelude ===============
    // 16 row-sweeps; thread t loads ints [4t..4t+3] of row r (8KB coalesced),
    // compresses to 4 bits, OR-combines across 8-lane groups, one write/group.
    {
        const int* mstage = Mb + (size_t)q0 * SEQ + 4 * t;
        i32x4 ms[4];
        #pragma unroll
        for (int r = 0; r < 4; ++r)
            ms[r] = *(const i32x4*)(mstage + (size_t)r * SEQ);
        #pragma unroll
        for (int r = 0; r < QBLK; ++r) {
            i32x4 cur = ms[r & 3];
            if (r + 4 < QBLK)
                ms[r & 3] = *(const i32x4*)(mstage + (size_t)(r + 4) * SEQ);
            unsigned v = nib4(cur) << (4 * (lane & 7));
            v |= __shfl_xor(v, 1);
            v |= __shfl_xor(v, 2);
            v |= __shfl_xor(v, 4);
            if ((lane & 7) == 0)
                su.mb[r][w * 8 + (lane >> 3)] = v;
        }
    }

    // =============== QK^T: pure K/L2 queue, 2-tile-ahead prefetch ===============
    unsigned sc_pk[2 * NCT];             // 64 scores, packed bf16, UNMASKED
    #pragma unroll
    for (int ct = 0; ct < NCT; ++ct) {
        bf16x8 kf0, kf1;
        if ((ct & 1) == 0) { kf0 = cvt8(krA[0], krA[1]); kf1 = cvt8(krA[2], krA[3]); }
        else               { kf0 = cvt8(krB[0], krB[1]); kf1 = cvt8(krB[2], krB[3]); }
        if (ct + 2 < NCT) {  // reload the freed buffer with tile ct+2
            const float* kn = Kb + (size_t)(wbase + (ct + 2) * 16 + c) * DIM + 8 * g;
            if ((ct & 1) == 0) {
                krA[0] = *(const f32x4*)(kn);      krA[1] = *(const f32x4*)(kn + 4);
                krA[2] = *(const f32x4*)(kn + 32); krA[3] = *(const f32x4*)(kn + 36);
            } else {
                krB[0] = *(const f32x4*)(kn);      krB[1] = *(const f32x4*)(kn + 4);
                krB[2] = *(const f32x4*)(kn + 32); krB[3] = *(const f32x4*)(kn + 36);
            }
        }
        f32x4 acc = {0.f, 0.f, 0.f, 0.f};
        __builtin_amdgcn_s_setprio(1);
        acc = __builtin_amdgcn_mfma_f32_16x16x32_bf16(kf0, qf[0], acc, 0, 0, 0);
        acc = __builtin_amdgcn_mfma_f32_16x16x32_bf16(kf1, qf[1], acc, 0, 0, 0);
        __builtin_amdgcn_s_setprio(0);
        sc_pk[2 * ct]     = bfbits(acc[0] * SCALE) | (bfbits(acc[1] * SCALE) << 16);
        sc_pk[2 * ct + 1] = bfbits(acc[2] * SCALE) | (bfbits(acc[3] * SCALE) << 16);
    }

    // ---- V chunk-0 prefetch: in flight across both barriers ----
    const int r_st = lane >> 4;
    const int cw   = (4 * c) & 15;
    const int ntw  = c >> 2;
    f32x4 vrawA[4], vrawB[4];
    {
        const float* vsrc = Vb + (size_t)(wbase + r_st) * DIM + 4 * c;
        #pragma unroll
        for (int i = 0; i < 4; ++i) {
            vrawA[i] = *(const f32x4*)(vsrc + (size_t)(4 * i) * DIM);
            vrawB[i] = *(const f32x4*)(vsrc + (size_t)(16 + 4 * i) * DIM);
        }
    }

    __syncthreads();   // barrier #1: mb bits visible

    // apply mask bits from LDS, bitwise on packed bf16 pairs
    const unsigned NEG2 = bfbits(-1e9f) | (bfbits(-1e9f) << 16);
    #pragma unroll
    for (int j = 0; j < 8; ++j) {
        unsigned word = su.mb[c][w * 8 + j];
        unsigned nibE = (word >> (4 * g)) & 0xFu;        // tile ct = 2j
        unsigned nibO = (word >> (16 + 4 * g)) & 0xFu;   // tile ct = 2j+1
        sc_pk[4 * j]     = mapply(sc_pk[4 * j],     nibE & 1u, nibE & 2u, NEG2);
        sc_pk[4 * j + 1] = mapply(sc_pk[4 * j + 1], nibE & 4u, nibE & 8u, NEG2);
        sc_pk[4 * j + 2] = mapply(sc_pk[4 * j + 2], nibO & 1u, nibO & 2u, NEG2);
        sc_pk[4 * j + 3] = mapply(sc_pk[4 * j + 3], nibO & 4u, nibO & 8u, NEG2);
    }

    // =============== single-exchange softmax: wave-local (mx, s_w) ===============
    float mx = -3e38f;
    #pragma unroll
    for (int i = 0; i < 2 * NCT; ++i)
        mx = fmaxf(mx, fmaxf(lo16(sc_pk[i]), hi16(sc_pk[i])));
    mx = fmaxf(mx, __shfl_xor(mx, 16));
    mx = fmaxf(mx, __shfl_xor(mx, 32));

    float sw_ = 0.f;
    #pragma unroll
    for (int i = 0; i < 2 * NCT; ++i) {
        float e0 = exp2f((lo16(sc_pk[i]) - mx) * LOG2E);
        float e1 = exp2f((hi16(sc_pk[i]) - mx) * LOG2E);
        sw_ += e0 + e1;
        sc_pk[i] = bfbits(e0) | (bfbits(e1) << 16);   // e' (wave-relative), bf16-packed
    }
    sw_ += __shfl_xor(sw_, 16);
    sw_ += __shfl_xor(sw_, 32);
    if (g == 0) { su.red_m[c][w] = mx; su.red_s[c][w] = sw_; }
    __syncthreads();   // barrier #2: (m,s) exchange

    float fac;
    {
        float M = su.red_m[c][0];
        #pragma unroll
        for (int i = 1; i < NWAVE; ++i) M = fmaxf(M, su.red_m[c][i]);
        float S = 0.f;
        #pragma unroll
        for (int i = 0; i < NWAVE; ++i)
            S += su.red_s[c][i] * exp2f((su.red_m[c][i] - M) * LOG2E);
        fac = exp2f((mx - M) * LOG2E) / S;
    }
    float facr[4];
    #pragma unroll
    for (int jr = 0; jr < 4; ++jr) facr[jr] = __shfl(fac, 4 * g + jr);

    // =============== PV + prob write; P-fragment via shfl ===============
    f32x4 cacc[4];
    #pragma unroll
    for (int nt = 0; nt < 4; ++nt) cacc[nt] = (f32x4){0.f, 0.f, 0.f, 0.f};

    const int  sA  = ((g & 1) << 5) + c;   // pf source lanes
    const int  sB  = sA + 16;
    const bool hiT = (g >> 1) != 0;

    float* prow = prob_out + ((size_t)bh * SEQ + (q0 + c)) * SEQ + wbase;
    __bf16* vbufW = su.sw[w].vbuf;

    #pragma unroll
    for (int cc = 0; cc < NCHUNK; ++cc) {
        // stage chunk loaded last iteration / prologue
        #pragma unroll
        for (int i = 0; i < 4; ++i) {
            ushort2 lo_, hi_;
            lo_.x = (unsigned short)bfbits(vrawA[i][0]);
            lo_.y = (unsigned short)bfbits(vrawA[i][1]);
            hi_.x = (unsigned short)bfbits(vrawA[i][2]);
            hi_.y = (unsigned short)bfbits(vrawA[i][3]);
            __bf16* p = &vbufW[ntw * NTSTR + (4 * i + r_st) * VPAD + cw];
            *(ushort2*)p = lo_;
            *(ushort2*)(p + 2) = hi_;
        }
        #pragma unroll
        for (int i = 0; i < 4; ++i) {
            ushort2 lo_, hi_;
            lo_.x = (unsigned short)bfbits(vrawB[i][0]);
            lo_.y = (unsigned short)bfbits(vrawB[i][1]);
            hi_.x = (unsigned short)bfbits(vrawB[i][2]);
            hi_.y = (unsigned short)bfbits(vrawB[i][3]);
            __bf16* p = &vbufW[ntw * NTSTR + (16 + 4 * i + r_st) * VPAD + cw];
            *(ushort2*)p = lo_;
            *(ushort2*)(p + 2) = hi_;
        }
        // issue NEXT chunk's loads
        if (cc + 1 < NCHUNK) {
            const float* vsrc = Vb + (size_t)(wbase + (cc + 1) * 32 + r_st) * DIM + 4 * c;
            #pragma unroll
            for (int i = 0; i < 4; ++i) {
                vrawA[i] = *(const f32x4*)(vsrc + (size_t)(4 * i) * DIM);
                vrawB[i] = *(const f32x4*)(vsrc + (size_t)(16 + 4 * i) * DIM);
            }
        }

        // prob writes: pn = e' * fac (normalized)
        unsigned w0 = sc_pk[4 * cc],     w1 = sc_pk[4 * cc + 1];
        unsigned w2 = sc_pk[4 * cc + 2], w3 = sc_pk[4 * cc + 3];
        {
            f32x4 pnA = { lo16(w0) * fac, hi16(w0) * fac, lo16(w1) * fac, hi16(w1) * fac };
            f32x4 pnB = { lo16(w2) * fac, hi16(w2) * fac, lo16(w3) * fac, hi16(w3) * fac };
            *(f32x4*)(prow + 32 * cc + 4 * g)      = pnA;
            *(f32x4*)(prow + 32 * cc + 16 + 4 * g) = pnB;
        }

        // P A-fragment via cross-lane shfl
        PFrag pf;
        {
            unsigned a0 = __shfl(w0, sA), b0 = __shfl(w2, sA);
            pf.w[0] = hiT ? b0 : a0;
            unsigned a1 = __shfl(w1, sA), b1 = __shfl(w3, sA);
            pf.w[1] = hiT ? b1 : a1;
            unsigned a2 = __shfl(w0, sB), b2 = __shfl(w2, sB);
            pf.w[2] = hiT ? b2 : a2;
            unsigned a3 = __shfl(w1, sB), b3 = __shfl(w3, sB);
            pf.w[3] = hiT ? b3 : a3;
        }

        // V B-frags: conflict-free scalar column reads
        bf16x8 vfr[4];
        #pragma unroll
        for (int nt = 0; nt < 4; ++nt) {
            bf16x8 f;
            #pragma unroll
            for (int j = 0; j < 8; ++j)
                f[j] = vbufW[nt * NTSTR + (8 * g + j) * VPAD + c];
            vfr[nt] = f;
        }

        __builtin_amdgcn_s_setprio(1);
        #pragma unroll
        for (int nt = 0; nt < 4; ++nt)
            cacc[nt] = __builtin_amdgcn_mfma_f32_16x16x32_bf16(pf.f, vfr[nt], cacc[nt], 0, 0, 0);
        __builtin_amdgcn_s_setprio(0);
    }

    // =============== ctx partials (scaled by per-row fac) + cross-wave reduce ===============
    #pragma unroll
    for (int nt = 0; nt < 4; ++nt)
        #pragma unroll
        for (int jr = 0; jr < 4; ++jr)
            su.sw[w].ctx[(4 * g + jr) * DIM + nt * 16 + c] = cacc[nt][jr] * facr[jr];
    __syncthreads();
    {
        int e = t * 2;
        float2 a = make_float2(0.f, 0.f);
        #pragma unroll
        for (int i = 0; i < NWAVE; ++i) {
            float2 v = *(const float2*)&su.sw[i].ctx[e];
            a.x += v.x; a.y += v.y;
        }
        *(float2*)(ctx_out + ((size_t)bh * SEQ + q0) * DIM + e) = a;
    }
}

extern "C" void kernel_launch(void* const* d_in, const int* in_sizes, int n_in,
                              void* d_out, int out_size, void* d_ws, size_t ws_size,
                              hipStream_t stream) {
    const float* Q = (const float*)d_in[0];
    const float* K = (const float*)d_in[1];
    const float* V = (const float*)d_in[2];
    const int* mask = (const int*)d_in[3];
    float* ctx  = (float*)d_out;
    float* prob = (float*)d_out + (size_t)4 * 16 * SEQ * DIM;

    dim3 grid(64 * (SEQ / QBLK));   // 8192, divisible by 8 XCDs
    dim3 block(THREADS);
    sdpa_mfma19<<<grid, block, 0, stream>>>(Q, K, V, mask, ctx, prob);
}